// Round 5
// baseline (471.521 us; speedup 1.0000x reference)
//
#include <hip/hip_runtime.h>

typedef __bf16 bf16;
typedef bf16  bf16x8 __attribute__((ext_vector_type(8)));
typedef bf16  bf16x4 __attribute__((ext_vector_type(4)));
typedef float f32x4  __attribute__((ext_vector_type(4)));
typedef unsigned int u32x2 __attribute__((ext_vector_type(2)));
typedef unsigned int u32x4 __attribute__((ext_vector_type(4)));

#define MFMA16(a, b, c) __builtin_amdgcn_mfma_f32_16x16x32_bf16((a), (b), (c), 0, 0, 0)
#define AS1 __attribute__((address_space(1)))
#define AS3 __attribute__((address_space(3)))

// async global->LDS, 16B per lane; LDS dest = (wave-uniform) base + lane*16
__device__ __forceinline__ void gld_lds16(const bf16* g, bf16* l) {
    __builtin_amdgcn_global_load_lds((AS1 void*)(g), (AS3 void*)(l), 16, 0, 0);
}

// XOR swizzle (all LDS tiles): [rows][32] 64B rows; logical chunk c of row r at c^((r>>1)&3).
// Staging permutes the GLOBAL source: logical chunk = (lane&3) ^ ((lane>>3)&3).

// ---------------- fused fp32 -> bf16 casts (x + 4 weights, one dispatch) ----------------
__global__ __launch_bounds__(256) void cvt_all(const float* __restrict__ x,
                                               const float* __restrict__ Wq, const float* __restrict__ Wk,
                                               const float* __restrict__ Wv, const float* __restrict__ Wu,
                                               bf16* ox, bf16* oq, bf16* ok, bf16* ov, bf16* ou,
                                               float sq, float sk) {
    int bid = blockIdx.x;
    const float* src; bf16* dst; float sc; int base;
    if (bid < 4096) { src = x; dst = ox; sc = 1.0f; base = bid; }
    else {
        int w = (bid - 4096) >> 10; base = (bid - 4096) & 1023;
        switch (w) {
            case 0:  src = Wq; dst = oq; sc = sq;   break;
            case 1:  src = Wk; dst = ok; sc = sk;   break;
            case 2:  src = Wv; dst = ov; sc = 1.0f; break;
            default: src = Wu; dst = ou; sc = 1.0f; break;
        }
    }
    int idx = (base * 256 + threadIdx.x) * 4;
    float4 v = *(const float4*)(src + idx);
    bf16x4 o;
    o[0] = (bf16)(v.x * sc); o[1] = (bf16)(v.y * sc);
    o[2] = (bf16)(v.z * sc); o[3] = (bf16)(v.w * sc);
    *(bf16x4*)(dst + idx) = o;
}

// ---------------- shared NT-GEMM core (R1-verified, 2-barrier): C[m,n] = sum_k A[m,k]*B[n,k] ----
// 128x128 tile, BK=32, K=1024. XOR-swizzled LDS. R3/R4 pipelining experiments were
// neutral-to-negative (dbuf +5us, 256^2 flat) -> reverted to the fastest measured config.
__device__ __forceinline__ void gemm_core(const bf16* __restrict__ A, const bf16* __restrict__ B,
                                          int mBase, int nBase, bf16* As, bf16* Bs,
                                          f32x4 acc[4][4]) {
    const int tid = threadIdx.x;
    const int wave = tid >> 6, lane = tid & 63;
    const int g = lane >> 4, lr = lane & 15;
    const int wm = (wave & 1) << 6, wn = (wave >> 1) << 6;
    const int q = lane >> 2;
    const int cswz = ((lane & 3) ^ ((lane >> 3) & 3)) << 3;
    const int pcs  = (g ^ ((lr >> 1) & 3)) << 3;

    const int rb0 = wave << 4, rb1 = rb0 + 64;
    const bf16* a0 = A + (size_t)(mBase + rb0 + q) * 1024 + cswz;
    const bf16* a1 = A + (size_t)(mBase + rb1 + q) * 1024 + cswz;
    const bf16* b0 = B + (size_t)(nBase + rb0 + q) * 1024 + cswz;
    const bf16* b1 = B + (size_t)(nBase + rb1 + q) * 1024 + cswz;

    for (int k0 = 0; k0 < 1024; k0 += 32) {
        __syncthreads();
        gld_lds16(a0 + k0, As + rb0 * 32);
        gld_lds16(a1 + k0, As + rb1 * 32);
        gld_lds16(b0 + k0, Bs + rb0 * 32);
        gld_lds16(b1 + k0, Bs + rb1 * 32);
        __syncthreads();

        bf16x8 af[4], bfr[4];
#pragma unroll
        for (int i = 0; i < 4; i++)
            af[i] = *(const bf16x8*)&As[(wm + (i << 4) + lr) * 32 + pcs];
#pragma unroll
        for (int j = 0; j < 4; j++)
            bfr[j] = *(const bf16x8*)&Bs[(wn + (j << 4) + lr) * 32 + pcs];
#pragma unroll
        for (int i = 0; i < 4; i++)
#pragma unroll
            for (int j = 0; j < 4; j++)
                acc[i][j] = MFMA16(af[i], bfr[j], acc[i][j]);
    }
}

// ---------------- merged QKV GEMM (R1-verified epilogues) ----------------
__global__ __launch_bounds__(256) void gemm_qkv(const bf16* __restrict__ X,
                                                const bf16* __restrict__ Wqk,  // [2048][1024]
                                                const bf16* __restrict__ Wv,
                                                bf16* __restrict__ Qo, bf16* __restrict__ Ko,
                                                bf16* __restrict__ Vto) {
    __shared__ bf16 As[128 * 32];
    __shared__ bf16 Bs[128 * 32];
    const int tid = threadIdx.x;
    const int wave = tid >> 6, lane = tid & 63;
    const int g = lane >> 4, lr = lane & 15;
    const int wm = (wave & 1) << 6, wn = (wave >> 1) << 6;
    const int my = blockIdx.y;
    const bool qk = (my < 16);

    const bf16* Ap = qk ? Wqk : X;
    const bf16* Bp = qk ? X   : Wv;
    const int mBase = qk ? my * 128 : blockIdx.x * 128;
    const int nBase = qk ? blockIdx.x * 128 : (my - 16) * 128;

    f32x4 acc[4][4] = {};
    gemm_core(Ap, Bp, mBase, nBase, As, Bs, acc);

    if (qk) {
#pragma unroll
        for (int i = 0; i < 4; i++) {
            int m0 = mBase + wm + (i << 4) + (g << 2);
            bf16* dst = (m0 >> 10) ? Ko : Qo;
            int feat = m0 & 1023;
            int h = feat >> 6, d = feat & 63;
#pragma unroll
            for (int j = 0; j < 4; j++) {
                int t = nBase + wn + (j << 4) + lr;
                int b = t >> 11, tl = t & 2047;
                bf16x4 v;
#pragma unroll
                for (int r = 0; r < 4; r++) v[r] = (bf16)acc[i][j][r];
                *(bf16x4*)&dst[(((size_t)((b << 4) + h) * 2048 + tl) << 6) + d] = v;
            }
        }
    } else {
#pragma unroll
        for (int i = 0; i < 4; i++) {
            int t0 = mBase + wm + (i << 4) + (g << 2);
            int b = t0 >> 11, tl = t0 & 2047;
#pragma unroll
            for (int j = 0; j < 4; j++) {
                int o = nBase + wn + (j << 4) + lr;
                int h = o >> 6, d = o & 63;
                bf16x4 v;
#pragma unroll
                for (int r = 0; r < 4; r++) v[r] = (bf16)acc[i][j][r];
                *(bf16x4*)&Vto[((size_t)(((b << 4) + h) << 6) + d) * 2048 + tl] = v;
            }
        }
    }
}

// ---------------- output GEMM (role-swapped): out = attn @ Wu^T + bu ----------------
__global__ __launch_bounds__(256) void gemm_out(const bf16* __restrict__ Wu, const bf16* __restrict__ A,
                                                const float* __restrict__ bias, float* __restrict__ out) {
    __shared__ bf16 As[128 * 32];
    __shared__ bf16 Bs[128 * 32];
    const int tid = threadIdx.x;
    const int wave = tid >> 6, lane = tid & 63;
    const int g = lane >> 4, lr = lane & 15;
    const int wm = (wave & 1) << 6, wn = (wave >> 1) << 6;
    const int mBase = blockIdx.y * 128, nBase = blockIdx.x * 128;

    f32x4 acc[4][4] = {};
    gemm_core(Wu, A, mBase, nBase, As, Bs, acc);

#pragma unroll
    for (int i = 0; i < 4; i++) {
        int o = mBase + wm + (i << 4) + (g << 2);
        float4 bv = *(const float4*)&bias[o];
#pragma unroll
        for (int j = 0; j < 4; j++) {
            int t = nBase + wn + (j << 4) + lr;
            float4 v;
            v.x = acc[i][j][0] + bv.x;
            v.y = acc[i][j][1] + bv.y;
            v.z = acc[i][j][2] + bv.z;
            v.w = acc[i][j][3] + bv.w;
            *(float4*)&out[((size_t)t << 10) + o] = v;
        }
    }
}

// ---------------- attention v7: (64t x 32s) wave tiles — 4x fragment reuse ----------------
// Block = one (b,h)-qblock pair, 64 t, 1024 blocks, XCD swizzle. Same staging/barriers as
// v6. Wave w owns ALL 64 t and the 32-s quarter w of each 128-s chunk: each kf/vf LDS
// fragment now feeds 4 MFMAs (4 t-tiles resident as qf[2][4]) -> b128 reads/iter/wave
// 16 -> 8 at unchanged 36 MFMA. exp2+permlane P-redistribution (R7-verified) unchanged,
// applied per (isub,tt). Cost: VGPR ~60 -> ~180 (2 blocks/CU) and a 4-way cross-wave
// endgame tree (3 barriers; rounds: {2->0, 3->1}, then split-halves {1->0 tt01, 0->1 tt23}).
__global__ __launch_bounds__(256, 2) void attn(const bf16* __restrict__ Q, const bf16* __restrict__ Kt,
                                               const bf16* __restrict__ Vt, bf16* __restrict__ O) {
    __shared__ bf16 Qs[2][64][32];    // 8KB [ks][t][d-half]; dead after qf -> L-dump area
    __shared__ bf16 Ks[2][128][32];   // 16KB [ks][s][d-half]; endgame O-dump A
    __shared__ bf16 Vs[4][64][32];    // 16KB [s-quarter][d][s-in-quarter]; endgame O-dump B

    const int tid = threadIdx.x;
    const int wave = tid >> 6, lane = tid & 63;
    const int g = lane >> 4, lr = lane & 15;
    const int q = lane >> 2;
    const int cswz = ((lane & 3) ^ ((lane >> 3) & 3)) << 3;
    const int pcs  = (g ^ ((lr >> 1) & 3)) << 3;

    const int bid = blockIdx.x;
    const int bh = ((bid & 7) << 2) | (bid >> 8);   // XCD-affinity
    const int qBase = ((bid >> 3) & 31) << 6;

    const bf16* Qg = Q + ((size_t)bh * 2048 + qBase) * 64;
    const bf16* Kg = Kt + (size_t)bh * 2048 * 64;
    const bf16* Vg = Vt + (size_t)bh * 64 * 2048;

    // stage Q: 8 batches of 1KB, 2 per wave, plane-split, swizzled source
#pragma unroll
    for (int i = 0; i < 2; i++) {
        int bi = (wave << 1) + i;
        int p = bi >> 2, rb = (bi & 3) << 4;
        gld_lds16(Qg + (rb + q) * 64 + (p << 5) + cswz, &Qs[p][rb][0]);
    }
    __syncthreads();

    bf16x8 qf[2][4];   // [ks][tt] — all 4 t-tiles resident
#pragma unroll
    for (int ks = 0; ks < 2; ks++)
#pragma unroll
        for (int tt = 0; tt < 4; tt++)
            qf[ks][tt] = *(const bf16x8*)&Qs[ks][(tt << 4) + lr][pcs];

    bf16x8 ones;
#pragma unroll
    for (int i = 0; i < 8; i++) ones[i] = (bf16)1.0f;

    f32x4 oacc[4][4] = {};   // [tt][jd]
    f32x4 oaccL[4] = {};

    for (int s0 = 0; s0 < 2048; s0 += 128) {
        __syncthreads();   // prior-iter kf/vf reads drained everywhere before re-stage
#pragma unroll
        for (int i = 0; i < 4; i++) {
            int bi = (wave << 2) + i;
            {   // K chunk: [2][128][32]
                int p = bi >> 3, rb = (bi & 7) << 4;
                gld_lds16(Kg + (size_t)(s0 + rb + q) * 64 + (p << 5) + cswz, &Ks[p][rb][0]);
            }
            {   // V chunk: [4][64][32]
                int p = bi >> 2, rb = (bi & 3) << 4;
                gld_lds16(Vg + (size_t)(rb + q) * 2048 + s0 + (p << 5) + cswz, &Vs[p][rb][0]);
            }
        }
        __syncthreads();

        // S^T for this wave's 32-s quarter x all 64 t
        f32x4 sacc[2][4] = {};   // [isub][tt]
#pragma unroll
        for (int ks = 0; ks < 2; ks++)
#pragma unroll
            for (int isub = 0; isub < 2; isub++) {
                bf16x8 kf = *(const bf16x8*)
                    &Ks[ks][(wave << 5) + (isub << 4) + lr][pcs];
#pragma unroll
                for (int tt = 0; tt < 4; tt++)
                    sacc[isub][tt] = MFMA16(kf, qf[ks][tt], sacc[isub][tt]);
            }
        // exp2 + in-register redistribution into PV A-fragments (no LDS)
        bf16x8 pf[4];
#pragma unroll
        for (int tt = 0; tt < 4; tt++) {
            bf16x4 e0, e1;
#pragma unroll
            for (int r = 0; r < 4; r++) {
                e0[r] = (bf16)__builtin_amdgcn_exp2f(sacc[0][tt][r]);   // s = 4g+r
                e1[r] = (bf16)__builtin_amdgcn_exp2f(sacc[1][tt][r]);   // s = 16+4g+r
            }
            u32x2 a = __builtin_bit_cast(u32x2, e0);
            u32x2 b = __builtin_bit_cast(u32x2, e1);
            u32x2 t0  = __builtin_amdgcn_permlane32_swap(a.x, b.x, false, false);
            u32x2 w02 = __builtin_amdgcn_permlane16_swap(t0.x, t0.y, false, false);
            u32x2 t1  = __builtin_amdgcn_permlane32_swap(a.y, b.y, false, false);
            u32x2 w13 = __builtin_amdgcn_permlane16_swap(t1.x, t1.y, false, false);
            u32x4 w = {w02.x, w13.x, w02.y, w13.y};
            pf[tt] = __builtin_bit_cast(bf16x8, w);   // P[t=lr][s=8g+j]
        }
        // O += P @ V; L += P @ ones (each vf feeds 4 MFMAs)
#pragma unroll
        for (int jd = 0; jd < 4; jd++) {
            bf16x8 vf = *(const bf16x8*)&Vs[wave][(jd << 4) + lr][pcs];
#pragma unroll
            for (int tt = 0; tt < 4; tt++)
                oacc[tt][jd] = MFMA16(pf[tt], vf, oacc[tt][jd]);
        }
#pragma unroll
        for (int tt = 0; tt < 4; tt++)
            oaccL[tt] = MFMA16(pf[tt], ones, oaccL[tt]);
    }

    // ---- endgame: 4-way cross-wave tree reduce ----
    __syncthreads();   // all waves done with Ks/Vs staging data
    float* OA = (float*)&Ks[0][0][0];   // 16KB
    float* OB = (float*)&Vs[0][0][0];   // 16KB
    float* LA = (float*)&Qs[0][0][0];   // 4KB
    float* LB = LA + 1024;              // 4KB

    // round 1: waves 2,3 dump; waves 0,1 add (0<-2 via OA, 1<-3 via OB)
    if (wave >= 2) {
        float* Od = (wave == 2) ? OA : OB;
        float* Ld = (wave == 2) ? LA : LB;
#pragma unroll
        for (int tt = 0; tt < 4; tt++) {
#pragma unroll
            for (int jd = 0; jd < 4; jd++)
                *(f32x4*)&Od[(((tt << 2) + jd) << 8) + (lane << 2)] = oacc[tt][jd];
            *(f32x4*)&Ld[(tt << 8) + (lane << 2)] = oaccL[tt];
        }
    }
    __syncthreads();
    if (wave < 2) {
        const float* Os = (wave == 0) ? OA : OB;
        const float* Ls = (wave == 0) ? LA : LB;
#pragma unroll
        for (int tt = 0; tt < 4; tt++) {
#pragma unroll
            for (int jd = 0; jd < 4; jd++)
                oacc[tt][jd] += *(const f32x4*)&Os[(((tt << 2) + jd) << 8) + (lane << 2)];
            oaccL[tt] += *(const f32x4*)&Ls[(tt << 8) + (lane << 2)];
        }
    }
    __syncthreads();   // round-1 reads done before round-2 overwrites
    // round 2: wave 1 dumps its tt{0,1} -> OA/LA; wave 0 dumps its tt{2,3} -> OB/LB
    if (wave < 2) {
        float* Od = (wave == 1) ? OA : OB;
        float* Ld = (wave == 1) ? LA : LB;
        const int tb = (wave == 1) ? 0 : 2;
#pragma unroll
        for (int ti = 0; ti < 2; ti++) {
#pragma unroll
            for (int jd = 0; jd < 4; jd++)
                *(f32x4*)&Od[(((ti << 2) + jd) << 8) + (lane << 2)] = oacc[tb + ti][jd];
            *(f32x4*)&Ld[(ti << 8) + (lane << 2)] = oaccL[tb + ti];
        }
    }
    __syncthreads();
    if (wave < 2) {
        const float* Os = (wave == 0) ? OA : OB;
        const float* Ls = (wave == 0) ? LA : LB;
        const int tb = (wave == 0) ? 0 : 2;   // wave0 finalizes tt{0,1} (+wave1's dump in OA)
        const int b = bh >> 4, h = bh & 15;
#pragma unroll
        for (int ti = 0; ti < 2; ti++) {
            const int tt = tb + ti;
            f32x4 Lp = *(const f32x4*)&Ls[(ti << 8) + (lane << 2)];
            f32x4 Lsum = oaccL[tt] + Lp;
            float linv[4];
#pragma unroll
            for (int r = 0; r < 4; r++) linv[r] = 1.0f / Lsum[r];
#pragma unroll
            for (int jd = 0; jd < 4; jd++) {
                f32x4 Op = *(const f32x4*)&Os[(((ti << 2) + jd) << 8) + (lane << 2)];
                f32x4 v = oacc[tt][jd] + Op;
#pragma unroll
                for (int r = 0; r < 4; r++) {
                    int t = qBase + (tt << 4) + (g << 2) + r;
                    int col = (h << 6) + (jd << 4) + lr;
                    O[(((size_t)(b * 2048 + t)) << 10) + col] = (bf16)(v[r] * linv[r]);
                }
            }
        }
    }
}

extern "C" void kernel_launch(void* const* d_in, const int* in_sizes, int n_in,
                              void* d_out, int out_size, void* d_ws, size_t ws_size,
                              hipStream_t stream) {
    const float* x  = (const float*)d_in[0];
    const float* Wq = (const float*)d_in[1];
    const float* Wk = (const float*)d_in[2];
    const float* Wv = (const float*)d_in[3];
    const float* Wu = (const float*)d_in[4];
    const float* bu = (const float*)d_in[5];
    float* out = (float*)d_out;

    char* ws = (char*)d_ws;
    bf16* xbf  = (bf16*)(ws);                      // 8MB; reused as attn output after QKV GEMM
    bf16* wqbf = (bf16*)(ws + ((size_t)8  << 20)); // wq+wk contiguous = stacked [2048][1024]
    bf16* wkbf = (bf16*)(ws + ((size_t)10 << 20));
    bf16* wvbf = (bf16*)(ws + ((size_t)12 << 20));
    bf16* wubf = (bf16*)(ws + ((size_t)14 << 20));
    bf16* Qb   = (bf16*)(ws + ((size_t)16 << 20)); // [b,h,t,d] 8MB
    bf16* Kb   = (bf16*)(ws + ((size_t)24 << 20)); // [b,h,t,d] 8MB
    bf16* Vtb  = (bf16*)(ws + ((size_t)32 << 20)); // [b,h,d,t] 8MB
    bf16* attnO = xbf;                             // overlay: x dead after gemm_qkv

    const float iscale_k = 0.17677669529663687f;   // 1024^-0.25
    const float iscale_q = 0.25503540109f;         // 1024^-0.25 * log2(e) -> scores in log2 domain

    cvt_all<<<8192, 256, 0, stream>>>(x, Wq, Wk, Wv, Wu, xbf, wqbf, wkbf, wvbf, wubf,
                                      iscale_q, iscale_k);

    gemm_qkv<<<dim3(32, 24), 256, 0, stream>>>(xbf, wqbf, wvbf, Qb, Kb, Vtb);
    attn<<<dim3(1024), 256, 0, stream>>>(Qb, Kb, Vtb, attnO);
    gemm_out<<<dim3(32, 8), 256, 0, stream>>>(wubf, attnO, bu, out);
}

// Round 7
// 189.389 us; speedup vs baseline: 2.4897x; 2.4897x over previous
//
#include <hip/hip_runtime.h>

typedef __bf16 bf16;
typedef bf16  bf16x8 __attribute__((ext_vector_type(8)));
typedef bf16  bf16x4 __attribute__((ext_vector_type(4)));
typedef float f32x4  __attribute__((ext_vector_type(4)));
typedef unsigned int u32x2 __attribute__((ext_vector_type(2)));
typedef unsigned int u32x4 __attribute__((ext_vector_type(4)));

#define MFMA16(a, b, c) __builtin_amdgcn_mfma_f32_16x16x32_bf16((a), (b), (c), 0, 0, 0)
#define AS1 __attribute__((address_space(1)))
#define AS3 __attribute__((address_space(3)))

// async global->LDS, 16B per lane; LDS dest = (wave-uniform) base + lane*16
__device__ __forceinline__ void gld_lds16(const bf16* g, bf16* l) {
    __builtin_amdgcn_global_load_lds((AS1 void*)(g), (AS3 void*)(l), 16, 0, 0);
}

// XOR swizzle (all LDS tiles): [rows][32] 64B rows; logical chunk c of row r at c^((r>>1)&3).
// Staging permutes the GLOBAL source: logical chunk = (lane&3) ^ ((lane>>3)&3).

// ---------------- fused fp32 -> bf16 casts (x + 4 weights, one dispatch) ----------------
__global__ __launch_bounds__(256) void cvt_all(const float* __restrict__ x,
                                               const float* __restrict__ Wq, const float* __restrict__ Wk,
                                               const float* __restrict__ Wv, const float* __restrict__ Wu,
                                               bf16* ox, bf16* oq, bf16* ok, bf16* ov, bf16* ou,
                                               float sq, float sk) {
    int bid = blockIdx.x;
    const float* src; bf16* dst; float sc; int base;
    if (bid < 4096) { src = x; dst = ox; sc = 1.0f; base = bid; }
    else {
        int w = (bid - 4096) >> 10; base = (bid - 4096) & 1023;
        switch (w) {
            case 0:  src = Wq; dst = oq; sc = sq;   break;
            case 1:  src = Wk; dst = ok; sc = sk;   break;
            case 2:  src = Wv; dst = ov; sc = 1.0f; break;
            default: src = Wu; dst = ou; sc = 1.0f; break;
        }
    }
    int idx = (base * 256 + threadIdx.x) * 4;
    float4 v = *(const float4*)(src + idx);
    bf16x4 o;
    o[0] = (bf16)(v.x * sc); o[1] = (bf16)(v.y * sc);
    o[2] = (bf16)(v.z * sc); o[3] = (bf16)(v.w * sc);
    *(bf16x4*)(dst + idx) = o;
}

// ---------------- shared NT-GEMM core (R1-verified, 2-barrier): C[m,n] = sum_k A[m,k]*B[n,k] ----
// 128x128 tile, BK=32, K=1024. XOR-swizzled LDS. R3/R4 pipelining experiments were
// neutral-to-negative (dbuf +5us, 256^2 flat) -> reverted to the fastest measured config.
__device__ __forceinline__ void gemm_core(const bf16* __restrict__ A, const bf16* __restrict__ B,
                                          int mBase, int nBase, bf16* As, bf16* Bs,
                                          f32x4 acc[4][4]) {
    const int tid = threadIdx.x;
    const int wave = tid >> 6, lane = tid & 63;
    const int g = lane >> 4, lr = lane & 15;
    const int wm = (wave & 1) << 6, wn = (wave >> 1) << 6;
    const int q = lane >> 2;
    const int cswz = ((lane & 3) ^ ((lane >> 3) & 3)) << 3;
    const int pcs  = (g ^ ((lr >> 1) & 3)) << 3;

    const int rb0 = wave << 4, rb1 = rb0 + 64;
    const bf16* a0 = A + (size_t)(mBase + rb0 + q) * 1024 + cswz;
    const bf16* a1 = A + (size_t)(mBase + rb1 + q) * 1024 + cswz;
    const bf16* b0 = B + (size_t)(nBase + rb0 + q) * 1024 + cswz;
    const bf16* b1 = B + (size_t)(nBase + rb1 + q) * 1024 + cswz;

    for (int k0 = 0; k0 < 1024; k0 += 32) {
        __syncthreads();
        gld_lds16(a0 + k0, As + rb0 * 32);
        gld_lds16(a1 + k0, As + rb1 * 32);
        gld_lds16(b0 + k0, Bs + rb0 * 32);
        gld_lds16(b1 + k0, Bs + rb1 * 32);
        __syncthreads();

        bf16x8 af[4], bfr[4];
#pragma unroll
        for (int i = 0; i < 4; i++)
            af[i] = *(const bf16x8*)&As[(wm + (i << 4) + lr) * 32 + pcs];
#pragma unroll
        for (int j = 0; j < 4; j++)
            bfr[j] = *(const bf16x8*)&Bs[(wn + (j << 4) + lr) * 32 + pcs];
#pragma unroll
        for (int i = 0; i < 4; i++)
#pragma unroll
            for (int j = 0; j < 4; j++)
                acc[i][j] = MFMA16(af[i], bfr[j], acc[i][j]);
    }
}

// ---------------- merged QKV GEMM (R1-verified epilogues) ----------------
__global__ __launch_bounds__(256) void gemm_qkv(const bf16* __restrict__ X,
                                                const bf16* __restrict__ Wqk,  // [2048][1024]
                                                const bf16* __restrict__ Wv,
                                                bf16* __restrict__ Qo, bf16* __restrict__ Ko,
                                                bf16* __restrict__ Vto) {
    __shared__ bf16 As[128 * 32];
    __shared__ bf16 Bs[128 * 32];
    const int tid = threadIdx.x;
    const int wave = tid >> 6, lane = tid & 63;
    const int g = lane >> 4, lr = lane & 15;
    const int wm = (wave & 1) << 6, wn = (wave >> 1) << 6;
    const int my = blockIdx.y;
    const bool qk = (my < 16);

    const bf16* Ap = qk ? Wqk : X;
    const bf16* Bp = qk ? X   : Wv;
    const int mBase = qk ? my * 128 : blockIdx.x * 128;
    const int nBase = qk ? blockIdx.x * 128 : (my - 16) * 128;

    f32x4 acc[4][4] = {};
    gemm_core(Ap, Bp, mBase, nBase, As, Bs, acc);

    if (qk) {
#pragma unroll
        for (int i = 0; i < 4; i++) {
            int m0 = mBase + wm + (i << 4) + (g << 2);
            bf16* dst = (m0 >> 10) ? Ko : Qo;
            int feat = m0 & 1023;
            int h = feat >> 6, d = feat & 63;
#pragma unroll
            for (int j = 0; j < 4; j++) {
                int t = nBase + wn + (j << 4) + lr;
                int b = t >> 11, tl = t & 2047;
                bf16x4 v;
#pragma unroll
                for (int r = 0; r < 4; r++) v[r] = (bf16)acc[i][j][r];
                *(bf16x4*)&dst[(((size_t)((b << 4) + h) * 2048 + tl) << 6) + d] = v;
            }
        }
    } else {
#pragma unroll
        for (int i = 0; i < 4; i++) {
            int t0 = mBase + wm + (i << 4) + (g << 2);
            int b = t0 >> 11, tl = t0 & 2047;
#pragma unroll
            for (int j = 0; j < 4; j++) {
                int o = nBase + wn + (j << 4) + lr;
                int h = o >> 6, d = o & 63;
                bf16x4 v;
#pragma unroll
                for (int r = 0; r < 4; r++) v[r] = (bf16)acc[i][j][r];
                *(bf16x4*)&Vto[((size_t)(((b << 4) + h) << 6) + d) * 2048 + tl] = v;
            }
        }
    }
}

// ---------------- output GEMM (role-swapped): out = attn @ Wu^T + bu ----------------
__global__ __launch_bounds__(256) void gemm_out(const bf16* __restrict__ Wu, const bf16* __restrict__ A,
                                                const float* __restrict__ bias, float* __restrict__ out) {
    __shared__ bf16 As[128 * 32];
    __shared__ bf16 Bs[128 * 32];
    const int tid = threadIdx.x;
    const int wave = tid >> 6, lane = tid & 63;
    const int g = lane >> 4, lr = lane & 15;
    const int wm = (wave & 1) << 6, wn = (wave >> 1) << 6;
    const int mBase = blockIdx.y * 128, nBase = blockIdx.x * 128;

    f32x4 acc[4][4] = {};
    gemm_core(Wu, A, mBase, nBase, As, Bs, acc);

#pragma unroll
    for (int i = 0; i < 4; i++) {
        int o = mBase + wm + (i << 4) + (g << 2);
        float4 bv = *(const float4*)&bias[o];
#pragma unroll
        for (int j = 0; j < 4; j++) {
            int t = nBase + wn + (j << 4) + lr;
            float4 v;
            v.x = acc[i][j][0] + bv.x;
            v.y = acc[i][j][1] + bv.y;
            v.z = acc[i][j][2] + bv.z;
            v.w = acc[i][j][3] + bv.w;
            *(float4*)&out[((size_t)t << 10) + o] = v;
        }
    }
}

// ---------------- attention v7b: (64t x 32s) wave tiles, STATIC-INDEXED endgame ----------------
// v7 (R5) was correct but 7x slow: endgame indexed oacc[tb+ti] with RUNTIME tb ->
// whole oacc array demoted to scratch (rule #20; VGPR 64, FETCH 535MB). v7b: identical
// structure, but round-2/final use explicit wave==0/1 branches with LITERAL oacc indices.
// Wave w owns all 64 t and the 32-s quarter w: each kf/vf feeds 4 MFMAs -> b128
// reads/iter/wave 16 -> 8 at unchanged 36 MFMA (vs v6: 16 reads, 2-MFMA reuse).
__global__ __launch_bounds__(256, 2) void attn(const bf16* __restrict__ Q, const bf16* __restrict__ Kt,
                                               const bf16* __restrict__ Vt, bf16* __restrict__ O) {
    __shared__ bf16 Qs[2][64][32];    // 8KB [ks][t][d-half]; dead after qf -> L-dump area
    __shared__ bf16 Ks[2][128][32];   // 16KB [ks][s][d-half]; endgame O-dump A
    __shared__ bf16 Vs[4][64][32];    // 16KB [s-quarter][d][s-in-quarter]; endgame O-dump B

    const int tid = threadIdx.x;
    const int wave = tid >> 6, lane = tid & 63;
    const int g = lane >> 4, lr = lane & 15;
    const int q = lane >> 2;
    const int cswz = ((lane & 3) ^ ((lane >> 3) & 3)) << 3;
    const int pcs  = (g ^ ((lr >> 1) & 3)) << 3;

    const int bid = blockIdx.x;
    const int bh = ((bid & 7) << 2) | (bid >> 8);   // XCD-affinity
    const int qBase = ((bid >> 3) & 31) << 6;

    const bf16* Qg = Q + ((size_t)bh * 2048 + qBase) * 64;
    const bf16* Kg = Kt + (size_t)bh * 2048 * 64;
    const bf16* Vg = Vt + (size_t)bh * 64 * 2048;

    // stage Q: 8 batches of 1KB, 2 per wave, plane-split, swizzled source
#pragma unroll
    for (int i = 0; i < 2; i++) {
        int bi = (wave << 1) + i;
        int p = bi >> 2, rb = (bi & 3) << 4;
        gld_lds16(Qg + (rb + q) * 64 + (p << 5) + cswz, &Qs[p][rb][0]);
    }
    __syncthreads();

    bf16x8 qf[2][4];   // [ks][tt] — all 4 t-tiles resident
#pragma unroll
    for (int ks = 0; ks < 2; ks++)
#pragma unroll
        for (int tt = 0; tt < 4; tt++)
            qf[ks][tt] = *(const bf16x8*)&Qs[ks][(tt << 4) + lr][pcs];

    bf16x8 ones;
#pragma unroll
    for (int i = 0; i < 8; i++) ones[i] = (bf16)1.0f;

    f32x4 oacc[4][4] = {};   // [tt][jd]
    f32x4 oaccL[4] = {};

    for (int s0 = 0; s0 < 2048; s0 += 128) {
        __syncthreads();   // prior-iter kf/vf reads drained everywhere before re-stage
#pragma unroll
        for (int i = 0; i < 4; i++) {
            int bi = (wave << 2) + i;
            {   // K chunk: [2][128][32]
                int p = bi >> 3, rb = (bi & 7) << 4;
                gld_lds16(Kg + (size_t)(s0 + rb + q) * 64 + (p << 5) + cswz, &Ks[p][rb][0]);
            }
            {   // V chunk: [4][64][32]
                int p = bi >> 2, rb = (bi & 3) << 4;
                gld_lds16(Vg + (size_t)(rb + q) * 2048 + s0 + (p << 5) + cswz, &Vs[p][rb][0]);
            }
        }
        __syncthreads();

        // S^T for this wave's 32-s quarter x all 64 t
        f32x4 sacc[2][4] = {};   // [isub][tt]
#pragma unroll
        for (int ks = 0; ks < 2; ks++)
#pragma unroll
            for (int isub = 0; isub < 2; isub++) {
                bf16x8 kf = *(const bf16x8*)
                    &Ks[ks][(wave << 5) + (isub << 4) + lr][pcs];
#pragma unroll
                for (int tt = 0; tt < 4; tt++)
                    sacc[isub][tt] = MFMA16(kf, qf[ks][tt], sacc[isub][tt]);
            }
        // exp2 + in-register redistribution into PV A-fragments (no LDS)
        bf16x8 pf[4];
#pragma unroll
        for (int tt = 0; tt < 4; tt++) {
            bf16x4 e0, e1;
#pragma unroll
            for (int r = 0; r < 4; r++) {
                e0[r] = (bf16)__builtin_amdgcn_exp2f(sacc[0][tt][r]);   // s = 4g+r
                e1[r] = (bf16)__builtin_amdgcn_exp2f(sacc[1][tt][r]);   // s = 16+4g+r
            }
            u32x2 a = __builtin_bit_cast(u32x2, e0);
            u32x2 b = __builtin_bit_cast(u32x2, e1);
            u32x2 t0  = __builtin_amdgcn_permlane32_swap(a.x, b.x, false, false);
            u32x2 w02 = __builtin_amdgcn_permlane16_swap(t0.x, t0.y, false, false);
            u32x2 t1  = __builtin_amdgcn_permlane32_swap(a.y, b.y, false, false);
            u32x2 w13 = __builtin_amdgcn_permlane16_swap(t1.x, t1.y, false, false);
            u32x4 w = {w02.x, w13.x, w02.y, w13.y};
            pf[tt] = __builtin_bit_cast(bf16x8, w);   // P[t=lr][s=8g+j]
        }
        // O += P @ V; L += P @ ones (each vf feeds 4 MFMAs)
#pragma unroll
        for (int jd = 0; jd < 4; jd++) {
            bf16x8 vf = *(const bf16x8*)&Vs[wave][(jd << 4) + lr][pcs];
#pragma unroll
            for (int tt = 0; tt < 4; tt++)
                oacc[tt][jd] = MFMA16(pf[tt], vf, oacc[tt][jd]);
        }
#pragma unroll
        for (int tt = 0; tt < 4; tt++)
            oaccL[tt] = MFMA16(pf[tt], ones, oaccL[tt]);
    }

    // ---- endgame: 4-way cross-wave tree reduce (ALL oacc indices compile-time) ----
    __syncthreads();   // all waves done with Ks/Vs staging data
    float* OA = (float*)&Ks[0][0][0];   // 16KB
    float* OB = (float*)&Vs[0][0][0];   // 16KB
    float* LA = (float*)&Qs[0][0][0];   // 4KB
    float* LB = LA + 1024;              // 4KB

    // round 1: waves 2,3 dump all tt; waves 0,1 add (0<-2 via OA, 1<-3 via OB)
    if (wave >= 2) {
        float* Od = (wave == 2) ? OA : OB;
        float* Ld = (wave == 2) ? LA : LB;
#pragma unroll
        for (int tt = 0; tt < 4; tt++) {
#pragma unroll
            for (int jd = 0; jd < 4; jd++)
                *(f32x4*)&Od[(((tt << 2) + jd) << 8) + (lane << 2)] = oacc[tt][jd];
            *(f32x4*)&Ld[(tt << 8) + (lane << 2)] = oaccL[tt];
        }
    }
    __syncthreads();
    if (wave < 2) {
        const float* Os = (wave == 0) ? OA : OB;
        const float* Ls = (wave == 0) ? LA : LB;
#pragma unroll
        for (int tt = 0; tt < 4; tt++) {
#pragma unroll
            for (int jd = 0; jd < 4; jd++)
                oacc[tt][jd] += *(const f32x4*)&Os[(((tt << 2) + jd) << 8) + (lane << 2)];
            oaccL[tt] += *(const f32x4*)&Ls[(tt << 8) + (lane << 2)];
        }
    }
    __syncthreads();   // round-1 reads done before round-2 overwrites
    // round 2: wave 1 dumps oacc[0..1] -> OA/LA; wave 0 dumps oacc[2..3] -> OB/LB.
    // Separate literal-index branches per wave (rule #20: no runtime base into oacc).
    if (wave == 1) {
#pragma unroll
        for (int ti = 0; ti < 2; ti++) {
#pragma unroll
            for (int jd = 0; jd < 4; jd++)
                *(f32x4*)&OA[(((ti << 2) + jd) << 8) + (lane << 2)] = oacc[0 + ti][jd];
            *(f32x4*)&LA[(ti << 8) + (lane << 2)] = oaccL[0 + ti];
        }
    } else if (wave == 0) {
#pragma unroll
        for (int ti = 0; ti < 2; ti++) {
#pragma unroll
            for (int jd = 0; jd < 4; jd++)
                *(f32x4*)&OB[(((ti << 2) + jd) << 8) + (lane << 2)] = oacc[2 + ti][jd];
            *(f32x4*)&LB[(ti << 8) + (lane << 2)] = oaccL[2 + ti];
        }
    }
    __syncthreads();
    // final: wave 0 finalizes tt{0,1} (+wave1's dump in OA); wave 1 finalizes tt{2,3} (OB)
    const int b = bh >> 4, h = bh & 15;
    if (wave == 0) {
#pragma unroll
        for (int ti = 0; ti < 2; ti++) {
            f32x4 Lp = *(const f32x4*)&LA[(ti << 8) + (lane << 2)];
            f32x4 Lsum = oaccL[0 + ti] + Lp;
            float linv[4];
#pragma unroll
            for (int r = 0; r < 4; r++) linv[r] = 1.0f / Lsum[r];
#pragma unroll
            for (int jd = 0; jd < 4; jd++) {
                f32x4 Op = *(const f32x4*)&OA[(((ti << 2) + jd) << 8) + (lane << 2)];
                f32x4 v = oacc[0 + ti][jd] + Op;
#pragma unroll
                for (int r = 0; r < 4; r++) {
                    int t = qBase + ((0 + ti) << 4) + (g << 2) + r;
                    int col = (h << 6) + (jd << 4) + lr;
                    O[(((size_t)(b * 2048 + t)) << 10) + col] = (bf16)(v[r] * linv[r]);
                }
            }
        }
    } else if (wave == 1) {
#pragma unroll
        for (int ti = 0; ti < 2; ti++) {
            f32x4 Lp = *(const f32x4*)&LB[(ti << 8) + (lane << 2)];
            f32x4 Lsum = oaccL[2 + ti] + Lp;
            float linv[4];
#pragma unroll
            for (int r = 0; r < 4; r++) linv[r] = 1.0f / Lsum[r];
#pragma unroll
            for (int jd = 0; jd < 4; jd++) {
                f32x4 Op = *(const f32x4*)&OB[(((ti << 2) + jd) << 8) + (lane << 2)];
                f32x4 v = oacc[2 + ti][jd] + Op;
#pragma unroll
                for (int r = 0; r < 4; r++) {
                    int t = qBase + ((2 + ti) << 4) + (g << 2) + r;
                    int col = (h << 6) + (jd << 4) + lr;
                    O[(((size_t)(b * 2048 + t)) << 10) + col] = (bf16)(v[r] * linv[r]);
                }
            }
        }
    }
}

extern "C" void kernel_launch(void* const* d_in, const int* in_sizes, int n_in,
                              void* d_out, int out_size, void* d_ws, size_t ws_size,
                              hipStream_t stream) {
    const float* x  = (const float*)d_in[0];
    const float* Wq = (const float*)d_in[1];
    const float* Wk = (const float*)d_in[2];
    const float* Wv = (const float*)d_in[3];
    const float* Wu = (const float*)d_in[4];
    const float* bu = (const float*)d_in[5];
    float* out = (float*)d_out;

    char* ws = (char*)d_ws;
    bf16* xbf  = (bf16*)(ws);                      // 8MB; reused as attn output after QKV GEMM
    bf16* wqbf = (bf16*)(ws + ((size_t)8  << 20)); // wq+wk contiguous = stacked [2048][1024]
    bf16* wkbf = (bf16*)(ws + ((size_t)10 << 20));
    bf16* wvbf = (bf16*)(ws + ((size_t)12 << 20));
    bf16* wubf = (bf16*)(ws + ((size_t)14 << 20));
    bf16* Qb   = (bf16*)(ws + ((size_t)16 << 20)); // [b,h,t,d] 8MB
    bf16* Kb   = (bf16*)(ws + ((size_t)24 << 20)); // [b,h,t,d] 8MB
    bf16* Vtb  = (bf16*)(ws + ((size_t)32 << 20)); // [b,h,d,t] 8MB
    bf16* attnO = xbf;                             // overlay: x dead after gemm_qkv

    const float iscale_k = 0.17677669529663687f;   // 1024^-0.25
    const float iscale_q = 0.25503540109f;         // 1024^-0.25 * log2(e) -> scores in log2 domain

    cvt_all<<<8192, 256, 0, stream>>>(x, Wq, Wk, Wv, Wu, xbf, wqbf, wkbf, wvbf, wubf,
                                      iscale_q, iscale_k);

    gemm_qkv<<<dim3(32, 24), 256, 0, stream>>>(xbf, wqbf, wvbf, Qb, Kb, Vtb);
    attn<<<dim3(1024), 256, 0, stream>>>(Qb, Kb, Vtb, attnO);
    gemm_out<<<dim3(32, 8), 256, 0, stream>>>(wubf, attnO, bu, out);
}

// Round 8
// 188.961 us; speedup vs baseline: 2.4953x; 1.0023x over previous
//
#include <hip/hip_runtime.h>

typedef __bf16 bf16;
typedef bf16  bf16x8 __attribute__((ext_vector_type(8)));
typedef bf16  bf16x4 __attribute__((ext_vector_type(4)));
typedef float f32x4  __attribute__((ext_vector_type(4)));
typedef unsigned int u32x2 __attribute__((ext_vector_type(2)));
typedef unsigned int u32x4 __attribute__((ext_vector_type(4)));

#define MFMA16(a, b, c) __builtin_amdgcn_mfma_f32_16x16x32_bf16((a), (b), (c), 0, 0, 0)
#define AS1 __attribute__((address_space(1)))
#define AS3 __attribute__((address_space(3)))

// async global->LDS, 16B per lane; LDS dest = (wave-uniform) base + lane*16
__device__ __forceinline__ void gld_lds16(const bf16* g, bf16* l) {
    __builtin_amdgcn_global_load_lds((AS1 void*)(g), (AS3 void*)(l), 16, 0, 0);
}

// XOR swizzle (all LDS tiles): [rows][32] 64B rows; logical chunk c of row r at c^((r>>1)&3).
// Staging permutes the GLOBAL source: logical chunk = (lane&3) ^ ((lane>>3)&3).

// ---------------- fused fp32 -> bf16 casts (x + 4 weights, one dispatch) ----------------
__global__ __launch_bounds__(256) void cvt_all(const float* __restrict__ x,
                                               const float* __restrict__ Wq, const float* __restrict__ Wk,
                                               const float* __restrict__ Wv, const float* __restrict__ Wu,
                                               bf16* ox, bf16* oq, bf16* ok, bf16* ov, bf16* ou,
                                               float sq, float sk) {
    int bid = blockIdx.x;
    const float* src; bf16* dst; float sc; int base;
    if (bid < 4096) { src = x; dst = ox; sc = 1.0f; base = bid; }
    else {
        int w = (bid - 4096) >> 10; base = (bid - 4096) & 1023;
        switch (w) {
            case 0:  src = Wq; dst = oq; sc = sq;   break;
            case 1:  src = Wk; dst = ok; sc = sk;   break;
            case 2:  src = Wv; dst = ov; sc = 1.0f; break;
            default: src = Wu; dst = ou; sc = 1.0f; break;
        }
    }
    int idx = (base * 256 + threadIdx.x) * 4;
    float4 v = *(const float4*)(src + idx);
    bf16x4 o;
    o[0] = (bf16)(v.x * sc); o[1] = (bf16)(v.y * sc);
    o[2] = (bf16)(v.z * sc); o[3] = (bf16)(v.w * sc);
    *(bf16x4*)(dst + idx) = o;
}

// ---------------- 128x128 NT-GEMM core (R1-verified, 2-barrier) — used by gemm_out ----------------
__device__ __forceinline__ void gemm_core(const bf16* __restrict__ A, const bf16* __restrict__ B,
                                          int mBase, int nBase, bf16* As, bf16* Bs,
                                          f32x4 acc[4][4]) {
    const int tid = threadIdx.x;
    const int wave = tid >> 6, lane = tid & 63;
    const int g = lane >> 4, lr = lane & 15;
    const int wm = (wave & 1) << 6, wn = (wave >> 1) << 6;
    const int q = lane >> 2;
    const int cswz = ((lane & 3) ^ ((lane >> 3) & 3)) << 3;
    const int pcs  = (g ^ ((lr >> 1) & 3)) << 3;

    const int rb0 = wave << 4, rb1 = rb0 + 64;
    const bf16* a0 = A + (size_t)(mBase + rb0 + q) * 1024 + cswz;
    const bf16* a1 = A + (size_t)(mBase + rb1 + q) * 1024 + cswz;
    const bf16* b0 = B + (size_t)(nBase + rb0 + q) * 1024 + cswz;
    const bf16* b1 = B + (size_t)(nBase + rb1 + q) * 1024 + cswz;

    for (int k0 = 0; k0 < 1024; k0 += 32) {
        __syncthreads();
        gld_lds16(a0 + k0, As + rb0 * 32);
        gld_lds16(a1 + k0, As + rb1 * 32);
        gld_lds16(b0 + k0, Bs + rb0 * 32);
        gld_lds16(b1 + k0, Bs + rb1 * 32);
        __syncthreads();

        bf16x8 af[4], bfr[4];
#pragma unroll
        for (int i = 0; i < 4; i++)
            af[i] = *(const bf16x8*)&As[(wm + (i << 4) + lr) * 32 + pcs];
#pragma unroll
        for (int j = 0; j < 4; j++)
            bfr[j] = *(const bf16x8*)&Bs[(wn + (j << 4) + lr) * 32 + pcs];
#pragma unroll
        for (int i = 0; i < 4; i++)
#pragma unroll
            for (int j = 0; j < 4; j++)
                acc[i][j] = MFMA16(af[i], bfr[j], acc[i][j]);
    }
}

// ---------------- merged QKV GEMM: 256x256 tile, BK=32, TRIPLE-buffer + counted vmcnt (R13) ----
// The T3+T4 structure proper: tile t computes from LDS slot t%3 while slot (t+1)%3 is
// already resident and slot (t+2)%3's 4 loads/wave stay IN FLIGHT across the tile-end
// barrier (s_waitcnt vmcnt(4), never 0 in the main loop — m218: counted vmcnt IS the
// 8-phase gain; R4's syncthreads-drain variant was the null config). Raw s_barrier
// (no implicit drain) + asm vmcnt with "memory" clobber (pins DMA issue order).
// Geometry/staging/fragment-addressing/epilogues byte-reused from R4 (passed).
// Hazards: stage(t)->slot (t+2)%3 disjoint from read slot t%3; slot t%3 only
// overwritten during t+1, after the barrier ending all its reads; vmcnt(4) before the
// tile-end barrier = slot (t+1)%3 landed block-wide (per-wave FIFO, 8 in flight).
__device__ __forceinline__ void stage_tile(const bf16* G, int k0, bf16* Ls,
                                           int wave, int q, int cswz) {
#pragma unroll
    for (int c = 0; c < 2; c++) {
        int rb = c * 8 + wave;          // 16-row block, 0..15
        gld_lds16(G + (size_t)(rb * 16 + q) * 1024 + k0 + cswz, Ls + rb * 16 * 32);
    }
}

__global__ __launch_bounds__(512, 1) void gemm_qkv(const bf16* __restrict__ X,
                                                   const bf16* __restrict__ Wqk,  // [2048][1024]
                                                   const bf16* __restrict__ Wv,
                                                   bf16* __restrict__ Qo, bf16* __restrict__ Ko,
                                                   bf16* __restrict__ Vto) {
    __shared__ bf16 As[3][256 * 32];   // 48KB, 3 slots
    __shared__ bf16 Bs[3][256 * 32];   // 48KB
    const int tid = threadIdx.x;
    const int wave = tid >> 6, lane = tid & 63;
    const int g = lane >> 4, lr = lane & 15;
    const int q = lane >> 2;
    const int cswz = ((lane & 3) ^ ((lane >> 3) & 3)) << 3;
    const int pcs  = (g ^ ((lr >> 1) & 3)) << 3;
    const int wm = wave >> 2, wn = wave & 3;

    const int bid = blockIdx.x;
    const bool qk = bid < 128;
    int mBase, nBase;
    const bf16 *Ap, *Bp;
    if (qk) { mBase = (bid >> 4) << 8; nBase = (bid & 15) << 8; Ap = Wqk; Bp = X; }
    else    { int v = bid - 128; mBase = (v >> 2) << 8; nBase = (v & 3) << 8; Ap = X; Bp = Wv; }

    const bf16* Ag = Ap + (size_t)mBase * 1024;
    const bf16* Bg = Bp + (size_t)nBase * 1024;

    f32x4 acc[8][4] = {};

    // prologue: tiles 0,1 -> slots 0,1 (8 loads/wave); wait tile0's 4, keep tile1's flying
    stage_tile(Ag, 0,  &As[0][0], wave, q, cswz);
    stage_tile(Bg, 0,  &Bs[0][0], wave, q, cswz);
    stage_tile(Ag, 32, &As[1][0], wave, q, cswz);
    stage_tile(Bg, 32, &Bs[1][0], wave, q, cswz);
    asm volatile("s_waitcnt vmcnt(4)" ::: "memory");
    __builtin_amdgcn_s_barrier();

    int cur = 0;
    for (int t = 0; t < 32; t++) {
        bf16* Ac = &As[cur][0];
        bf16* Bc = &Bs[cur][0];
        const int nx2 = (cur >= 1) ? cur - 1 : 2;   // (cur+2)%3
        const int k2 = (t + 2) << 5;
        const bool pre = (t < 30);

        // phase 0: read B(all) + A(mh0); issue A(t+2); MFMA quadrant mh0
        bf16x8 bfr[4], af[4];
#pragma unroll
        for (int j = 0; j < 4; j++)
            bfr[j] = *(const bf16x8*)&Bc[(wn * 64 + (j << 4) + lr) * 32 + pcs];
#pragma unroll
        for (int i = 0; i < 4; i++)
            af[i] = *(const bf16x8*)&Ac[(wm * 128 + (i << 4) + lr) * 32 + pcs];
        if (pre) stage_tile(Ag, k2, &As[nx2][0], wave, q, cswz);
        __builtin_amdgcn_s_barrier();
        __builtin_amdgcn_s_setprio(1);
#pragma unroll
        for (int i = 0; i < 4; i++)
#pragma unroll
            for (int j = 0; j < 4; j++)
                acc[i][j] = MFMA16(af[i], bfr[j], acc[i][j]);
        __builtin_amdgcn_s_setprio(0);

        // phase 1: read A(mh1); issue B(t+2); MFMA quadrant mh1
#pragma unroll
        for (int i = 0; i < 4; i++)
            af[i] = *(const bf16x8*)&Ac[(wm * 128 + 64 + (i << 4) + lr) * 32 + pcs];
        if (pre) stage_tile(Bg, k2, &Bs[nx2][0], wave, q, cswz);
        __builtin_amdgcn_s_barrier();
        __builtin_amdgcn_s_setprio(1);
#pragma unroll
        for (int i = 0; i < 4; i++)
#pragma unroll
            for (int j = 0; j < 4; j++)
                acc[4 + i][j] = MFMA16(af[i], bfr[j], acc[4 + i][j]);
        __builtin_amdgcn_s_setprio(0);

        // tile boundary: next slot landed; t+2's 4 loads stay in flight (counted!)
        if (pre) asm volatile("s_waitcnt vmcnt(4)" ::: "memory");
        else     asm volatile("s_waitcnt vmcnt(0)" ::: "memory");
        __builtin_amdgcn_s_barrier();
        cur = (cur >= 2) ? 0 : cur + 1;
    }

    if (qk) {
#pragma unroll
        for (int i = 0; i < 8; i++) {
            int m0 = mBase + wm * 128 + (i << 4) + (g << 2);
            bf16* dst = (m0 >> 10) ? Ko : Qo;
            int feat = m0 & 1023;
            int h = feat >> 6, d = feat & 63;
#pragma unroll
            for (int j = 0; j < 4; j++) {
                int tt = nBase + wn * 64 + (j << 4) + lr;
                int b = tt >> 11, tl = tt & 2047;
                bf16x4 v;
#pragma unroll
                for (int r = 0; r < 4; r++) v[r] = (bf16)acc[i][j][r];
                *(bf16x4*)&dst[(((size_t)((b << 4) + h) * 2048 + tl) << 6) + d] = v;
            }
        }
    } else {
#pragma unroll
        for (int i = 0; i < 8; i++) {
            int t0 = mBase + wm * 128 + (i << 4) + (g << 2);
            int b = t0 >> 11, tl = t0 & 2047;
#pragma unroll
            for (int j = 0; j < 4; j++) {
                int o = nBase + wn * 64 + (j << 4) + lr;
                int h = o >> 6, d = o & 63;
                bf16x4 v;
#pragma unroll
                for (int r = 0; r < 4; r++) v[r] = (bf16)acc[i][j][r];
                *(bf16x4*)&Vto[((size_t)(((b << 4) + h) << 6) + d) * 2048 + tl] = v;
            }
        }
    }
}

// ---------------- output GEMM (role-swapped): out = attn @ Wu^T + bu ----------------
__global__ __launch_bounds__(256) void gemm_out(const bf16* __restrict__ Wu, const bf16* __restrict__ A,
                                                const float* __restrict__ bias, float* __restrict__ out) {
    __shared__ bf16 As[128 * 32];
    __shared__ bf16 Bs[128 * 32];
    const int tid = threadIdx.x;
    const int wave = tid >> 6, lane = tid & 63;
    const int g = lane >> 4, lr = lane & 15;
    const int wm = (wave & 1) << 6, wn = (wave >> 1) << 6;
    const int mBase = blockIdx.y * 128, nBase = blockIdx.x * 128;

    f32x4 acc[4][4] = {};
    gemm_core(Wu, A, mBase, nBase, As, Bs, acc);

#pragma unroll
    for (int i = 0; i < 4; i++) {
        int o = mBase + wm + (i << 4) + (g << 2);
        float4 bv = *(const float4*)&bias[o];
#pragma unroll
        for (int j = 0; j < 4; j++) {
            int t = nBase + wn + (j << 4) + lr;
            float4 v;
            v.x = acc[i][j][0] + bv.x;
            v.y = acc[i][j][1] + bv.y;
            v.z = acc[i][j][2] + bv.z;
            v.w = acc[i][j][3] + bv.w;
            *(float4*)&out[((size_t)t << 10) + o] = v;
        }
    }
}

// ---------------- attention v6 (R7-best, 47.2us): in-register P via permlane16/32_swap ----------
// v7b (64t x 32s re-tile) FALSIFIED in R7: 52.9us, occupancy 29->18.6% — latency hiding
// lost more than LDS traffic gained. Reverted to v6: (32t x 64s) wave tiles, 4 blocks/CU.
__global__ __launch_bounds__(256, 4) void attn(const bf16* __restrict__ Q, const bf16* __restrict__ Kt,
                                               const bf16* __restrict__ Vt, bf16* __restrict__ O) {
    __shared__ bf16 Qs[2][64][32];    // 8KB [ks][t][d-half]; dead after qf
    __shared__ bf16 Ks[2][128][32];   // 16KB [ks][s][d-half]
    __shared__ bf16 Vs[4][64][32];    // 16KB [s32-block][d][s-quarter]

    const int tid = threadIdx.x;
    const int wave = tid >> 6, lane = tid & 63;
    const int g = lane >> 4, lr = lane & 15;
    const int q = lane >> 2;
    const int cswz = ((lane & 3) ^ ((lane >> 3) & 3)) << 3;
    const int pcs  = (g ^ ((lr >> 1) & 3)) << 3;
    const int pair = wave >> 1;       // t-half (32 t)
    const int shalf = wave & 1;       // s-half (64 s per 128-chunk)

    const int bid = blockIdx.x;
    const int bh = ((bid & 7) << 2) | (bid >> 8);   // XCD-affinity
    const int qBase = ((bid >> 3) & 31) << 6;

    const bf16* Qg = Q + ((size_t)bh * 2048 + qBase) * 64;
    const bf16* Kg = Kt + (size_t)bh * 2048 * 64;
    const bf16* Vg = Vt + (size_t)bh * 64 * 2048;

    // stage Q: 8 batches of 1KB, 2 per wave, plane-split, swizzled source
#pragma unroll
    for (int i = 0; i < 2; i++) {
        int bi = (wave << 1) + i;
        int p = bi >> 2, rb = (bi & 3) << 4;
        gld_lds16(Qg + (rb + q) * 64 + (p << 5) + cswz, &Qs[p][rb][0]);
    }
    __syncthreads();

    bf16x8 qf[2][2];   // [ks][tt] — this wave's 2 t-tiles
#pragma unroll
    for (int ks = 0; ks < 2; ks++)
#pragma unroll
        for (int tt = 0; tt < 2; tt++)
            qf[ks][tt] = *(const bf16x8*)&Qs[ks][(pair << 5) + (tt << 4) + lr][pcs];

    bf16x8 ones;
#pragma unroll
    for (int i = 0; i < 8; i++) ones[i] = (bf16)1.0f;

    f32x4 oacc[2][4] = {};   // [tt][jd]
    f32x4 oaccL[2] = {};

    for (int s0 = 0; s0 < 2048; s0 += 128) {
        __syncthreads();   // all waves' Ks/Vs (and initial qf) reads drained before re-stage
#pragma unroll
        for (int i = 0; i < 4; i++) {
            int bi = (wave << 2) + i;
            {   // K chunk: [2][128][32]
                int p = bi >> 3, rb = (bi & 7) << 4;
                gld_lds16(Kg + (size_t)(s0 + rb + q) * 64 + (p << 5) + cswz, &Ks[p][rb][0]);
            }
            {   // V chunk: [4][64][32]
                int p = bi >> 2, rb = (bi & 3) << 4;
                gld_lds16(Vg + (size_t)(rb + q) * 2048 + s0 + (p << 5) + cswz, &Vs[p][rb][0]);
            }
        }
        __syncthreads();

#pragma unroll
        for (int sblk = 0; sblk < 2; sblk++) {
            // S^T for this wave's 32-s sub-slice x its 32 t
            f32x4 sacc[2][2] = {};   // [isub][tt]
#pragma unroll
            for (int ks = 0; ks < 2; ks++)
#pragma unroll
                for (int isub = 0; isub < 2; isub++) {
                    bf16x8 kf = *(const bf16x8*)
                        &Ks[ks][(shalf << 6) + (sblk << 5) + (isub << 4) + lr][pcs];
                    sacc[isub][0] = MFMA16(kf, qf[ks][0], sacc[isub][0]);
                    sacc[isub][1] = MFMA16(kf, qf[ks][1], sacc[isub][1]);
                }
            // exp2 + in-register redistribution into PV A-fragments (no LDS)
            bf16x8 pf[2];
#pragma unroll
            for (int tt = 0; tt < 2; tt++) {
                bf16x4 e0, e1;
#pragma unroll
                for (int r = 0; r < 4; r++) {
                    e0[r] = (bf16)__builtin_amdgcn_exp2f(sacc[0][tt][r]);   // s = 4g+r
                    e1[r] = (bf16)__builtin_amdgcn_exp2f(sacc[1][tt][r]);   // s = 16+4g+r
                }
                u32x2 a = __builtin_bit_cast(u32x2, e0);
                u32x2 b = __builtin_bit_cast(u32x2, e1);
                u32x2 t0  = __builtin_amdgcn_permlane32_swap(a.x, b.x, false, false);
                u32x2 w02 = __builtin_amdgcn_permlane16_swap(t0.x, t0.y, false, false);
                u32x2 t1  = __builtin_amdgcn_permlane32_swap(a.y, b.y, false, false);
                u32x2 w13 = __builtin_amdgcn_permlane16_swap(t1.x, t1.y, false, false);
                u32x4 w = {w02.x, w13.x, w02.y, w13.y};
                pf[tt] = __builtin_bit_cast(bf16x8, w);   // P[t=lr][s=8g+j]
            }
            // O += P @ V; L += P @ ones
#pragma unroll
            for (int jd = 0; jd < 4; jd++) {
                bf16x8 vf = *(const bf16x8*)&Vs[(shalf << 1) + sblk][(jd << 4) + lr][pcs];
                oacc[0][jd] = MFMA16(pf[0], vf, oacc[0][jd]);
                oacc[1][jd] = MFMA16(pf[1], vf, oacc[1][jd]);
            }
            oaccL[0] = MFMA16(pf[0], ones, oaccL[0]);
            oaccL[1] = MFMA16(pf[1], ones, oaccL[1]);
        }
    }

    // ---- endgame: 2-way cross-wave reduce (s-half partners share a t-pair) ----
    __syncthreads();   // all waves done with Ks/Vs
    float* Odump = (float*)&Ks[0][0][0];   // 16KB = 2 pairs x 2048 floats
    float* Ldump = (float*)&Vs[0][0][0];   // 4KB used
    if (shalf == 1) {
#pragma unroll
        for (int tt = 0; tt < 2; tt++) {
#pragma unroll
            for (int jd = 0; jd < 4; jd++)
                *(f32x4*)&Odump[(pair << 11) + (((tt << 2) + jd) << 8) + (lane << 2)] = oacc[tt][jd];
            *(f32x4*)&Ldump[(pair << 9) + (tt << 8) + (lane << 2)] = oaccL[tt];
        }
    }
    __syncthreads();
    if (shalf == 0) {
        const int b = bh >> 4, h = bh & 15;
#pragma unroll
        for (int tt = 0; tt < 2; tt++) {
            f32x4 Lp = *(const f32x4*)&Ldump[(pair << 9) + (tt << 8) + (lane << 2)];
            f32x4 Ls = oaccL[tt] + Lp;
            float linv[4];
#pragma unroll
            for (int r = 0; r < 4; r++) linv[r] = 1.0f / Ls[r];
#pragma unroll
            for (int jd = 0; jd < 4; jd++) {
                f32x4 Op = *(const f32x4*)&Odump[(pair << 11) + (((tt << 2) + jd) << 8) + (lane << 2)];
                f32x4 v = oacc[tt][jd] + Op;
#pragma unroll
                for (int r = 0; r < 4; r++) {
                    int t = qBase + (pair << 5) + (tt << 4) + (g << 2) + r;
                    int col = (h << 6) + (jd << 4) + lr;
                    O[(((size_t)(b * 2048 + t)) << 10) + col] = (bf16)(v[r] * linv[r]);
                }
            }
        }
    }
}

extern "C" void kernel_launch(void* const* d_in, const int* in_sizes, int n_in,
                              void* d_out, int out_size, void* d_ws, size_t ws_size,
                              hipStream_t stream) {
    const float* x  = (const float*)d_in[0];
    const float* Wq = (const float*)d_in[1];
    const float* Wk = (const float*)d_in[2];
    const float* Wv = (const float*)d_in[3];
    const float* Wu = (const float*)d_in[4];
    const float* bu = (const float*)d_in[5];
    float* out = (float*)d_out;

    char* ws = (char*)d_ws;
    bf16* xbf  = (bf16*)(ws);                      // 8MB; reused as attn output after QKV GEMM
    bf16* wqbf = (bf16*)(ws + ((size_t)8  << 20)); // wq+wk contiguous = stacked [2048][1024]
    bf16* wkbf = (bf16*)(ws + ((size_t)10 << 20));
    bf16* wvbf = (bf16*)(ws + ((size_t)12 << 20));
    bf16* wubf = (bf16*)(ws + ((size_t)14 << 20));
    bf16* Qb   = (bf16*)(ws + ((size_t)16 << 20)); // [b,h,t,d] 8MB
    bf16* Kb   = (bf16*)(ws + ((size_t)24 << 20)); // [b,h,t,d] 8MB
    bf16* Vtb  = (bf16*)(ws + ((size_t)32 << 20)); // [b,h,d,t] 8MB
    bf16* attnO = xbf;                             // overlay: x dead after gemm_qkv

    const float iscale_k = 0.17677669529663687f;   // 1024^-0.25
    const float iscale_q = 0.25503540109f;         // 1024^-0.25 * log2(e) -> scores in log2 domain

    cvt_all<<<8192, 256, 0, stream>>>(x, Wq, Wk, Wv, Wu, xbf, wqbf, wkbf, wvbf, wubf,
                                      iscale_q, iscale_k);

    gemm_qkv<<<dim3(192), 512, 0, stream>>>(xbf, wqbf, wvbf, Qb, Kb, Vtb);
    attn<<<dim3(1024), 256, 0, stream>>>(Qb, Kb, Vtb, attnO);
    gemm_out<<<dim3(32, 8), 256, 0, stream>>>(wubf, attnO, bu, out);
}

// Round 9
// 178.207 us; speedup vs baseline: 2.6459x; 1.0603x over previous
//
#include <hip/hip_runtime.h>

typedef __bf16 bf16;
typedef bf16  bf16x8 __attribute__((ext_vector_type(8)));
typedef bf16  bf16x4 __attribute__((ext_vector_type(4)));
typedef float f32x4  __attribute__((ext_vector_type(4)));
typedef unsigned int u32x2 __attribute__((ext_vector_type(2)));
typedef unsigned int u32x4 __attribute__((ext_vector_type(4)));

#define MFMA16(a, b, c) __builtin_amdgcn_mfma_f32_16x16x32_bf16((a), (b), (c), 0, 0, 0)
#define AS1 __attribute__((address_space(1)))
#define AS3 __attribute__((address_space(3)))

// async global->LDS, 16B per lane; LDS dest = (wave-uniform) base + lane*16
__device__ __forceinline__ void gld_lds16(const bf16* g, bf16* l) {
    __builtin_amdgcn_global_load_lds((AS1 void*)(g), (AS3 void*)(l), 16, 0, 0);
}

// XOR swizzle (all LDS tiles): [rows][32] 64B rows; logical chunk c of row r at c^((r>>1)&3).
// Staging permutes the GLOBAL source: logical chunk = (lane&3) ^ ((lane>>3)&3).

// ---------------- fused fp32 -> bf16 casts (x + 4 weights, one dispatch) ----------------
__global__ __launch_bounds__(256) void cvt_all(const float* __restrict__ x,
                                               const float* __restrict__ Wq, const float* __restrict__ Wk,
                                               const float* __restrict__ Wv, const float* __restrict__ Wu,
                                               bf16* ox, bf16* oq, bf16* ok, bf16* ov, bf16* ou,
                                               float sq, float sk) {
    int bid = blockIdx.x;
    const float* src; bf16* dst; float sc; int base;
    if (bid < 4096) { src = x; dst = ox; sc = 1.0f; base = bid; }
    else {
        int w = (bid - 4096) >> 10; base = (bid - 4096) & 1023;
        switch (w) {
            case 0:  src = Wq; dst = oq; sc = sq;   break;
            case 1:  src = Wk; dst = ok; sc = sk;   break;
            case 2:  src = Wv; dst = ov; sc = 1.0f; break;
            default: src = Wu; dst = ou; sc = 1.0f; break;
        }
    }
    int idx = (base * 256 + threadIdx.x) * 4;
    float4 v = *(const float4*)(src + idx);
    bf16x4 o;
    o[0] = (bf16)(v.x * sc); o[1] = (bf16)(v.y * sc);
    o[2] = (bf16)(v.z * sc); o[3] = (bf16)(v.w * sc);
    *(bf16x4*)(dst + idx) = o;
}

// ---------------- 128x128 NT-GEMM core, 2-barrier (R1-verified BEST) — used by gemm_qkv ----------
// qkv runs 768 blocks at 3/CU: cross-block TLP already pipelines this structure. Three
// restructures (R3 dbuf, R4 256^2-2phase, R8 256^2 counted-vmcnt) all measured <= this.
__device__ __forceinline__ void gemm_core(const bf16* __restrict__ A, const bf16* __restrict__ B,
                                          int mBase, int nBase, bf16* As, bf16* Bs,
                                          f32x4 acc[4][4]) {
    const int tid = threadIdx.x;
    const int wave = tid >> 6, lane = tid & 63;
    const int g = lane >> 4, lr = lane & 15;
    const int wm = (wave & 1) << 6, wn = (wave >> 1) << 6;
    const int q = lane >> 2;
    const int cswz = ((lane & 3) ^ ((lane >> 3) & 3)) << 3;
    const int pcs  = (g ^ ((lr >> 1) & 3)) << 3;

    const int rb0 = wave << 4, rb1 = rb0 + 64;
    const bf16* a0 = A + (size_t)(mBase + rb0 + q) * 1024 + cswz;
    const bf16* a1 = A + (size_t)(mBase + rb1 + q) * 1024 + cswz;
    const bf16* b0 = B + (size_t)(nBase + rb0 + q) * 1024 + cswz;
    const bf16* b1 = B + (size_t)(nBase + rb1 + q) * 1024 + cswz;

    for (int k0 = 0; k0 < 1024; k0 += 32) {
        __syncthreads();
        gld_lds16(a0 + k0, As + rb0 * 32);
        gld_lds16(a1 + k0, As + rb1 * 32);
        gld_lds16(b0 + k0, Bs + rb0 * 32);
        gld_lds16(b1 + k0, Bs + rb1 * 32);
        __syncthreads();

        bf16x8 af[4], bfr[4];
#pragma unroll
        for (int i = 0; i < 4; i++)
            af[i] = *(const bf16x8*)&As[(wm + (i << 4) + lr) * 32 + pcs];
#pragma unroll
        for (int j = 0; j < 4; j++)
            bfr[j] = *(const bf16x8*)&Bs[(wn + (j << 4) + lr) * 32 + pcs];
#pragma unroll
        for (int i = 0; i < 4; i++)
#pragma unroll
            for (int j = 0; j < 4; j++)
                acc[i][j] = MFMA16(af[i], bfr[j], acc[i][j]);
    }
}

// ---------------- 128x128 NT-GEMM core, DBUF single-barrier (R3-verified) — gemm_out only ----------
// gemm_out is grid-starved: 256 blocks = 1 block/CU, zero cross-block TLP -> the 2-barrier
// drain exposes full staging latency each K-step. Dbuf overlaps next-tile DMA with MFMA;
// the end-of-iter __syncthreads (vmcnt0+lgkm0 drain) waits on loads that flew across the
// whole compute phase. (R3 applied this to BOTH gemms: net +3.3us; qkv's TLP made it lose
// there. This round de-confounds: dbuf ONLY where TLP is absent.)
__device__ __forceinline__ void gemm_core_dbuf(const bf16* __restrict__ A, const bf16* __restrict__ B,
                                               int mBase, int nBase, bf16* As, bf16* Bs,
                                               f32x4 acc[4][4]) {
    const int tid = threadIdx.x;
    const int wave = tid >> 6, lane = tid & 63;
    const int g = lane >> 4, lr = lane & 15;
    const int wm = (wave & 1) << 6, wn = (wave >> 1) << 6;
    const int q = lane >> 2;
    const int cswz = ((lane & 3) ^ ((lane >> 3) & 3)) << 3;
    const int pcs  = (g ^ ((lr >> 1) & 3)) << 3;

    const int rb0 = wave << 4, rb1 = rb0 + 64;
    const bf16* a0 = A + (size_t)(mBase + rb0 + q) * 1024 + cswz;
    const bf16* a1 = A + (size_t)(mBase + rb1 + q) * 1024 + cswz;
    const bf16* b0 = B + (size_t)(nBase + rb0 + q) * 1024 + cswz;
    const bf16* b1 = B + (size_t)(nBase + rb1 + q) * 1024 + cswz;

    // prologue: stage tile 0 into buffer 0
    gld_lds16(a0, As + rb0 * 32);
    gld_lds16(a1, As + rb1 * 32);
    gld_lds16(b0, Bs + rb0 * 32);
    gld_lds16(b1, Bs + rb1 * 32);
    __syncthreads();

    for (int k0 = 0; k0 < 1024; k0 += 32) {
        const int cur = (k0 >> 5) & 1;
        bf16* Asc = As + cur * (128 * 32);
        bf16* Bsc = Bs + cur * (128 * 32);
        if (k0 + 32 < 1024) {
            bf16* Asn = As + (cur ^ 1) * (128 * 32);
            bf16* Bsn = Bs + (cur ^ 1) * (128 * 32);
            gld_lds16(a0 + k0 + 32, Asn + rb0 * 32);
            gld_lds16(a1 + k0 + 32, Asn + rb1 * 32);
            gld_lds16(b0 + k0 + 32, Bsn + rb0 * 32);
            gld_lds16(b1 + k0 + 32, Bsn + rb1 * 32);
        }

        bf16x8 af[4], bfr[4];
#pragma unroll
        for (int i = 0; i < 4; i++)
            af[i] = *(const bf16x8*)&Asc[(wm + (i << 4) + lr) * 32 + pcs];
#pragma unroll
        for (int j = 0; j < 4; j++)
            bfr[j] = *(const bf16x8*)&Bsc[(wn + (j << 4) + lr) * 32 + pcs];
#pragma unroll
        for (int i = 0; i < 4; i++)
#pragma unroll
            for (int j = 0; j < 4; j++)
                acc[i][j] = MFMA16(af[i], bfr[j], acc[i][j]);

        __syncthreads();   // one barrier/iter: orders reads-done + drains next-tile DMA
    }
}

// ---------------- merged QKV GEMM (R1-verified BEST config) ----------------
__global__ __launch_bounds__(256) void gemm_qkv(const bf16* __restrict__ X,
                                                const bf16* __restrict__ Wqk,  // [2048][1024]
                                                const bf16* __restrict__ Wv,
                                                bf16* __restrict__ Qo, bf16* __restrict__ Ko,
                                                bf16* __restrict__ Vto) {
    __shared__ bf16 As[128 * 32];
    __shared__ bf16 Bs[128 * 32];
    const int tid = threadIdx.x;
    const int wave = tid >> 6, lane = tid & 63;
    const int g = lane >> 4, lr = lane & 15;
    const int wm = (wave & 1) << 6, wn = (wave >> 1) << 6;
    const int my = blockIdx.y;
    const bool qk = (my < 16);

    const bf16* Ap = qk ? Wqk : X;
    const bf16* Bp = qk ? X   : Wv;
    const int mBase = qk ? my * 128 : blockIdx.x * 128;
    const int nBase = qk ? blockIdx.x * 128 : (my - 16) * 128;

    f32x4 acc[4][4] = {};
    gemm_core(Ap, Bp, mBase, nBase, As, Bs, acc);

    if (qk) {
#pragma unroll
        for (int i = 0; i < 4; i++) {
            int m0 = mBase + wm + (i << 4) + (g << 2);
            bf16* dst = (m0 >> 10) ? Ko : Qo;
            int feat = m0 & 1023;
            int h = feat >> 6, d = feat & 63;
#pragma unroll
            for (int j = 0; j < 4; j++) {
                int t = nBase + wn + (j << 4) + lr;
                int b = t >> 11, tl = t & 2047;
                bf16x4 v;
#pragma unroll
                for (int r = 0; r < 4; r++) v[r] = (bf16)acc[i][j][r];
                *(bf16x4*)&dst[(((size_t)((b << 4) + h) * 2048 + tl) << 6) + d] = v;
            }
        }
    } else {
#pragma unroll
        for (int i = 0; i < 4; i++) {
            int t0 = mBase + wm + (i << 4) + (g << 2);
            int b = t0 >> 11, tl = t0 & 2047;
#pragma unroll
            for (int j = 0; j < 4; j++) {
                int o = nBase + wn + (j << 4) + lr;
                int h = o >> 6, d = o & 63;
                bf16x4 v;
#pragma unroll
                for (int r = 0; r < 4; r++) v[r] = (bf16)acc[i][j][r];
                *(bf16x4*)&Vto[((size_t)(((b << 4) + h) << 6) + d) * 2048 + tl] = v;
            }
        }
    }
}

// ---------------- output GEMM (role-swapped, DBUF core): out = attn @ Wu^T + bu ----------------
__global__ __launch_bounds__(256) void gemm_out(const bf16* __restrict__ Wu, const bf16* __restrict__ A,
                                                const float* __restrict__ bias, float* __restrict__ out) {
    __shared__ bf16 As[2][128 * 32];
    __shared__ bf16 Bs[2][128 * 32];
    const int tid = threadIdx.x;
    const int wave = tid >> 6, lane = tid & 63;
    const int g = lane >> 4, lr = lane & 15;
    const int wm = (wave & 1) << 6, wn = (wave >> 1) << 6;
    const int mBase = blockIdx.y * 128, nBase = blockIdx.x * 128;

    f32x4 acc[4][4] = {};
    gemm_core_dbuf(Wu, A, mBase, nBase, &As[0][0], &Bs[0][0], acc);

#pragma unroll
    for (int i = 0; i < 4; i++) {
        int o = mBase + wm + (i << 4) + (g << 2);
        float4 bv = *(const float4*)&bias[o];
#pragma unroll
        for (int j = 0; j < 4; j++) {
            int t = nBase + wn + (j << 4) + lr;
            float4 v;
            v.x = acc[i][j][0] + bv.x;
            v.y = acc[i][j][1] + bv.y;
            v.z = acc[i][j][2] + bv.z;
            v.w = acc[i][j][3] + bv.w;
            *(float4*)&out[((size_t)t << 10) + o] = v;
        }
    }
}

// ---------------- attention v6 (R7/R8-best, 47.2us): in-register P via permlane16/32_swap --------
__global__ __launch_bounds__(256, 4) void attn(const bf16* __restrict__ Q, const bf16* __restrict__ Kt,
                                               const bf16* __restrict__ Vt, bf16* __restrict__ O) {
    __shared__ bf16 Qs[2][64][32];    // 8KB [ks][t][d-half]; dead after qf
    __shared__ bf16 Ks[2][128][32];   // 16KB [ks][s][d-half]
    __shared__ bf16 Vs[4][64][32];    // 16KB [s32-block][d][s-quarter]

    const int tid = threadIdx.x;
    const int wave = tid >> 6, lane = tid & 63;
    const int g = lane >> 4, lr = lane & 15;
    const int q = lane >> 2;
    const int cswz = ((lane & 3) ^ ((lane >> 3) & 3)) << 3;
    const int pcs  = (g ^ ((lr >> 1) & 3)) << 3;
    const int pair = wave >> 1;       // t-half (32 t)
    const int shalf = wave & 1;       // s-half (64 s per 128-chunk)

    const int bid = blockIdx.x;
    const int bh = ((bid & 7) << 2) | (bid >> 8);   // XCD-affinity
    const int qBase = ((bid >> 3) & 31) << 6;

    const bf16* Qg = Q + ((size_t)bh * 2048 + qBase) * 64;
    const bf16* Kg = Kt + (size_t)bh * 2048 * 64;
    const bf16* Vg = Vt + (size_t)bh * 64 * 2048;

    // stage Q: 8 batches of 1KB, 2 per wave, plane-split, swizzled source
#pragma unroll
    for (int i = 0; i < 2; i++) {
        int bi = (wave << 1) + i;
        int p = bi >> 2, rb = (bi & 3) << 4;
        gld_lds16(Qg + (rb + q) * 64 + (p << 5) + cswz, &Qs[p][rb][0]);
    }
    __syncthreads();

    bf16x8 qf[2][2];   // [ks][tt] — this wave's 2 t-tiles
#pragma unroll
    for (int ks = 0; ks < 2; ks++)
#pragma unroll
        for (int tt = 0; tt < 2; tt++)
            qf[ks][tt] = *(const bf16x8*)&Qs[ks][(pair << 5) + (tt << 4) + lr][pcs];

    bf16x8 ones;
#pragma unroll
    for (int i = 0; i < 8; i++) ones[i] = (bf16)1.0f;

    f32x4 oacc[2][4] = {};   // [tt][jd]
    f32x4 oaccL[2] = {};

    for (int s0 = 0; s0 < 2048; s0 += 128) {
        __syncthreads();   // all waves' Ks/Vs (and initial qf) reads drained before re-stage
#pragma unroll
        for (int i = 0; i < 4; i++) {
            int bi = (wave << 2) + i;
            {   // K chunk: [2][128][32]
                int p = bi >> 3, rb = (bi & 7) << 4;
                gld_lds16(Kg + (size_t)(s0 + rb + q) * 64 + (p << 5) + cswz, &Ks[p][rb][0]);
            }
            {   // V chunk: [4][64][32]
                int p = bi >> 2, rb = (bi & 3) << 4;
                gld_lds16(Vg + (size_t)(rb + q) * 2048 + s0 + (p << 5) + cswz, &Vs[p][rb][0]);
            }
        }
        __syncthreads();

#pragma unroll
        for (int sblk = 0; sblk < 2; sblk++) {
            // S^T for this wave's 32-s sub-slice x its 32 t
            f32x4 sacc[2][2] = {};   // [isub][tt]
#pragma unroll
            for (int ks = 0; ks < 2; ks++)
#pragma unroll
                for (int isub = 0; isub < 2; isub++) {
                    bf16x8 kf = *(const bf16x8*)
                        &Ks[ks][(shalf << 6) + (sblk << 5) + (isub << 4) + lr][pcs];
                    sacc[isub][0] = MFMA16(kf, qf[ks][0], sacc[isub][0]);
                    sacc[isub][1] = MFMA16(kf, qf[ks][1], sacc[isub][1]);
                }
            // exp2 + in-register redistribution into PV A-fragments (no LDS)
            bf16x8 pf[2];
#pragma unroll
            for (int tt = 0; tt < 2; tt++) {
                bf16x4 e0, e1;
#pragma unroll
                for (int r = 0; r < 4; r++) {
                    e0[r] = (bf16)__builtin_amdgcn_exp2f(sacc[0][tt][r]);   // s = 4g+r
                    e1[r] = (bf16)__builtin_amdgcn_exp2f(sacc[1][tt][r]);   // s = 16+4g+r
                }
                u32x2 a = __builtin_bit_cast(u32x2, e0);
                u32x2 b = __builtin_bit_cast(u32x2, e1);
                u32x2 t0  = __builtin_amdgcn_permlane32_swap(a.x, b.x, false, false);
                u32x2 w02 = __builtin_amdgcn_permlane16_swap(t0.x, t0.y, false, false);
                u32x2 t1  = __builtin_amdgcn_permlane32_swap(a.y, b.y, false, false);
                u32x2 w13 = __builtin_amdgcn_permlane16_swap(t1.x, t1.y, false, false);
                u32x4 w = {w02.x, w13.x, w02.y, w13.y};
                pf[tt] = __builtin_bit_cast(bf16x8, w);   // P[t=lr][s=8g+j]
            }
            // O += P @ V; L += P @ ones
#pragma unroll
            for (int jd = 0; jd < 4; jd++) {
                bf16x8 vf = *(const bf16x8*)&Vs[(shalf << 1) + sblk][(jd << 4) + lr][pcs];
                oacc[0][jd] = MFMA16(pf[0], vf, oacc[0][jd]);
                oacc[1][jd] = MFMA16(pf[1], vf, oacc[1][jd]);
            }
            oaccL[0] = MFMA16(pf[0], ones, oaccL[0]);
            oaccL[1] = MFMA16(pf[1], ones, oaccL[1]);
        }
    }

    // ---- endgame: 2-way cross-wave reduce (s-half partners share a t-pair) ----
    __syncthreads();   // all waves done with Ks/Vs
    float* Odump = (float*)&Ks[0][0][0];   // 16KB = 2 pairs x 2048 floats
    float* Ldump = (float*)&Vs[0][0][0];   // 4KB used
    if (shalf == 1) {
#pragma unroll
        for (int tt = 0; tt < 2; tt++) {
#pragma unroll
            for (int jd = 0; jd < 4; jd++)
                *(f32x4*)&Odump[(pair << 11) + (((tt << 2) + jd) << 8) + (lane << 2)] = oacc[tt][jd];
            *(f32x4*)&Ldump[(pair << 9) + (tt << 8) + (lane << 2)] = oaccL[tt];
        }
    }
    __syncthreads();
    if (shalf == 0) {
        const int b = bh >> 4, h = bh & 15;
#pragma unroll
        for (int tt = 0; tt < 2; tt++) {
            f32x4 Lp = *(const f32x4*)&Ldump[(pair << 9) + (tt << 8) + (lane << 2)];
            f32x4 Ls = oaccL[tt] + Lp;
            float linv[4];
#pragma unroll
            for (int r = 0; r < 4; r++) linv[r] = 1.0f / Ls[r];
#pragma unroll
            for (int jd = 0; jd < 4; jd++) {
                f32x4 Op = *(const f32x4*)&Odump[(pair << 11) + (((tt << 2) + jd) << 8) + (lane << 2)];
                f32x4 v = oacc[tt][jd] + Op;
#pragma unroll
                for (int r = 0; r < 4; r++) {
                    int t = qBase + (pair << 5) + (tt << 4) + (g << 2) + r;
                    int col = (h << 6) + (jd << 4) + lr;
                    O[(((size_t)(b * 2048 + t)) << 10) + col] = (bf16)(v[r] * linv[r]);
                }
            }
        }
    }
}

extern "C" void kernel_launch(void* const* d_in, const int* in_sizes, int n_in,
                              void* d_out, int out_size, void* d_ws, size_t ws_size,
                              hipStream_t stream) {
    const float* x  = (const float*)d_in[0];
    const float* Wq = (const float*)d_in[1];
    const float* Wk = (const float*)d_in[2];
    const float* Wv = (const float*)d_in[3];
    const float* Wu = (const float*)d_in[4];
    const float* bu = (const float*)d_in[5];
    float* out = (float*)d_out;

    char* ws = (char*)d_ws;
    bf16* xbf  = (bf16*)(ws);                      // 8MB; reused as attn output after QKV GEMM
    bf16* wqbf = (bf16*)(ws + ((size_t)8  << 20)); // wq+wk contiguous = stacked [2048][1024]
    bf16* wkbf = (bf16*)(ws + ((size_t)10 << 20));
    bf16* wvbf = (bf16*)(ws + ((size_t)12 << 20));
    bf16* wubf = (bf16*)(ws + ((size_t)14 << 20));
    bf16* Qb   = (bf16*)(ws + ((size_t)16 << 20)); // [b,h,t,d] 8MB
    bf16* Kb   = (bf16*)(ws + ((size_t)24 << 20)); // [b,h,t,d] 8MB
    bf16* Vtb  = (bf16*)(ws + ((size_t)32 << 20)); // [b,h,d,t] 8MB
    bf16* attnO = xbf;                             // overlay: x dead after gemm_qkv

    const float iscale_k = 0.17677669529663687f;   // 1024^-0.25
    const float iscale_q = 0.25503540109f;         // 1024^-0.25 * log2(e) -> scores in log2 domain

    cvt_all<<<8192, 256, 0, stream>>>(x, Wq, Wk, Wv, Wu, xbf, wqbf, wkbf, wvbf, wubf,
                                      iscale_q, iscale_k);

    gemm_qkv<<<dim3(32, 24), 256, 0, stream>>>(xbf, wqbf, wvbf, Qb, Kb, Vtb);
    attn<<<dim3(1024), 256, 0, stream>>>(Qb, Kb, Vtb, attnO);
    gemm_out<<<dim3(32, 8), 256, 0, stream>>>(wubf, attnO, bu, out);
}